// Round 1
// baseline (529.641 us; speedup 1.0000x reference)
//
#include <hip/hip_runtime.h>
#include <hip/hip_bf16.h>
#include <stdint.h>

// Problem: x[65536][256] f32, memory[2048][256] f32
// out = [ memory_output[65536][256] | attention_weights[65536][2048] ] f32
#define NQ 65536
#define MM 2048
#define DD 256

typedef __bf16 bf16x8 __attribute__((ext_vector_type(8)));
typedef float f32x4 __attribute__((ext_vector_type(4)));
typedef unsigned short u16;
typedef unsigned int u32;

typedef __attribute__((address_space(3))) u32 lds_u32;
typedef __attribute__((address_space(1))) u32 glb_u32;

// global -> LDS direct 16B load. LDS dest must be wave-uniform; HW writes
// base + lane*16. Generic->AS3 truncation is valid (4GB-aligned aperture).
#define GLOAD16(gsrc, ldst)                                                    \
  __builtin_amdgcn_global_load_lds((glb_u32*)(uintptr_t)(gsrc),                \
                                   (lds_u32*)(u32)(uintptr_t)(ldst), 16, 0, 0)

// Convert memory to bf16 (RTNE) in both row-major [2048][256] and transposed
// [256][2048] layouts (transposed feeds the PV B-operand as contiguous 16B).
__global__ __launch_bounds__(256) void mem_convert_kernel(
    const float* __restrict__ memory, u16* __restrict__ memb,
    u16* __restrict__ memTb) {
  int tid = blockIdx.x * 256 + threadIdx.x;  // 524288 total
  float v = memory[tid];
  u32 u = __builtin_bit_cast(u32, v);
  u += 0x7FFFu + ((u >> 16) & 1u);  // round-to-nearest-even
  u16 b = (u16)(u >> 16);
  memb[tid] = b;
  int m = tid >> 8, d = tid & 255;
  memTb[d * MM + m] = b;
}

// Fused: per block 64 q-rows (4 waves x 16). Phase 1: exp-sum over all
// memory tiles. Phase 2: recompute scores, write weights, accumulate O.
__global__ __launch_bounds__(256) void fused_kernel(
    const float* __restrict__ x, const u16* __restrict__ memb,
    const u16* __restrict__ memTb, float* __restrict__ outO,
    float* __restrict__ outW) {
  // Tiles are linear (global_load_lds requirement) with 16B-chunk XOR swizzle
  // chunk^ (row&7) applied on BOTH the pre-swizzled global source and reads.
  __shared__ __align__(16) u16 lds_mem[64 * 256];   // mem rows, 512B/row
  __shared__ __align__(16) u16 lds_memT[256 * 64];  // memT rows, 128B/row
  __shared__ __align__(16) u16 plds[4][16][72];     // per-wave P, padded 64->72

  const int tid = threadIdx.x;
  const int wv = tid >> 6;
  const int l = tid & 63;
  const int g = l >> 4;  // 0..3
  const int c = l & 15;  // 0..15
  const int qw = blockIdx.x * 64 + wv * 16;

  // ---- Q fragments: 16 rows x 256 dims per wave, bf16 A-frags in regs ----
  bf16x8 aq[8];
  {
    const float* xrow = x + (size_t)(qw + c) * DD;
#pragma unroll
    for (int ks = 0; ks < 8; ++ks) {
      const float4 f0 = *(const float4*)(xrow + ks * 32 + g * 8);
      const float4 f1 = *(const float4*)(xrow + ks * 32 + g * 8 + 4);
      bf16x8 a;
      a[0] = (__bf16)f0.x; a[1] = (__bf16)f0.y;
      a[2] = (__bf16)f0.z; a[3] = (__bf16)f0.w;
      a[4] = (__bf16)f1.x; a[5] = (__bf16)f1.y;
      a[6] = (__bf16)f1.z; a[7] = (__bf16)f1.w;
      aq[ks] = a;
    }
  }

  // ---- Phase 1: row sums of exp(scores) (no max-sub: |s| bounded ~3) ----
  float part[4] = {0.f, 0.f, 0.f, 0.f};
  for (int mt = 0; mt < 32; ++mt) {
    __syncthreads();
#pragma unroll
    for (int i = 0; i < 8; ++i) {
      const int wc = wv * 8 + i;          // wave-chunk 0..31 (1KB each)
      const int row = wc * 2 + (l >> 5);  // 0..63
      const int csrc = (l & 31) ^ (row & 7);
      const u16* src = memb + (((size_t)(mt * 64 + row)) << 8) + csrc * 8;
      GLOAD16(src, (char*)lds_mem + (wc << 10));
    }
    __syncthreads();
#pragma unroll
    for (int msub = 0; msub < 4; ++msub) {
      const int mrow = msub * 16 + c;
      const char* bbase = (const char*)lds_mem + mrow * 512;
      f32x4 acc = {0.f, 0.f, 0.f, 0.f};
#pragma unroll
      for (int ks = 0; ks < 8; ++ks) {
        const int ch = (ks * 4 + g) ^ (mrow & 7);
        bf16x8 bf = *(const bf16x8*)(bbase + (ch << 4));
        acc = __builtin_amdgcn_mfma_f32_16x16x32_bf16(aq[ks], bf, acc, 0, 0, 0);
      }
#pragma unroll
      for (int r = 0; r < 4; ++r) part[r] += __expf(acc[r]);
    }
  }
  // reduce across the 16 lanes sharing each q row (lane-group = l>>4)
  float invs[4];
#pragma unroll
  for (int r = 0; r < 4; ++r) {
    float p = part[r];
    p += __shfl_xor(p, 1, 64);
    p += __shfl_xor(p, 2, 64);
    p += __shfl_xor(p, 4, 64);
    p += __shfl_xor(p, 8, 64);
    invs[r] = 1.0f / p;
  }

  // ---- Phase 2: recompute scores, write W, accumulate O = W*M ----
  f32x4 oacc[16];
#pragma unroll
  for (int i = 0; i < 16; ++i) oacc[i] = (f32x4){0.f, 0.f, 0.f, 0.f};

  for (int mt = 0; mt < 32; ++mt) {
    __syncthreads();
#pragma unroll
    for (int i = 0; i < 8; ++i) {  // stage mem rows [mt*64, +64)
      const int wc = wv * 8 + i;
      const int row = wc * 2 + (l >> 5);
      const int csrc = (l & 31) ^ (row & 7);
      const u16* src = memb + (((size_t)(mt * 64 + row)) << 8) + csrc * 8;
      GLOAD16(src, (char*)lds_mem + (wc << 10));
    }
#pragma unroll
    for (int i = 0; i < 8; ++i) {  // stage memT cols [mt*64, +64) (all 256 d)
      const int wc = wv * 8 + i;
      const int gci = (wc << 6) + l;
      const int d = gci >> 3;
      const int csrc = (gci & 7) ^ (d & 7);
      const u16* src = memTb + (size_t)d * MM + mt * 64 + csrc * 8;
      GLOAD16(src, (char*)lds_memT + (wc << 10));
    }
    __syncthreads();

#pragma unroll
    for (int msub = 0; msub < 4; ++msub) {
      const int mrow = msub * 16 + c;
      const char* bbase = (const char*)lds_mem + mrow * 512;
      f32x4 acc = {0.f, 0.f, 0.f, 0.f};
#pragma unroll
      for (int ks = 0; ks < 8; ++ks) {
        const int ch = (ks * 4 + g) ^ (mrow & 7);
        bf16x8 bf = *(const bf16x8*)(bbase + (ch << 4));
        acc = __builtin_amdgcn_mfma_f32_16x16x32_bf16(aq[ks], bf, acc, 0, 0, 0);
      }
#pragma unroll
      for (int r = 0; r < 4; ++r) {
        const float wgt = __expf(acc[r]) * invs[r];
        outW[(size_t)(qw + g * 4 + r) * MM + mt * 64 + msub * 16 + c] = wgt;
        plds[wv][g * 4 + r][msub * 16 + c] = __builtin_bit_cast(u16, (__bf16)wgt);
      }
    }

    // wave-private P roundtrip: DS ops are in-order per wave; drain before read
    asm volatile("s_waitcnt lgkmcnt(0)" ::: "memory");

#pragma unroll
    for (int ks2 = 0; ks2 < 2; ++ks2) {
      bf16x8 pa = *(const bf16x8*)&plds[wv][c][ks2 * 32 + g * 8];
#pragma unroll
      for (int dsub = 0; dsub < 16; ++dsub) {
        const int drow = dsub * 16 + c;
        const char* tb = (const char*)lds_memT + drow * 128;
        const int ch = (ks2 * 4 + g) ^ (drow & 7);
        bf16x8 bf = *(const bf16x8*)(tb + (ch << 4));
        oacc[dsub] =
            __builtin_amdgcn_mfma_f32_16x16x32_bf16(pa, bf, oacc[dsub], 0, 0, 0);
      }
    }
  }

#pragma unroll
  for (int dsub = 0; dsub < 16; ++dsub) {
#pragma unroll
    for (int r = 0; r < 4; ++r) {
      outO[(size_t)(qw + g * 4 + r) * DD + dsub * 16 + c] = oacc[dsub][r];
    }
  }
}

extern "C" void kernel_launch(void* const* d_in, const int* in_sizes, int n_in,
                              void* d_out, int out_size, void* d_ws,
                              size_t ws_size, hipStream_t stream) {
  const float* x = (const float*)d_in[0];
  const float* memory = (const float*)d_in[1];
  float* outO = (float*)d_out;                      // [65536][256]
  float* outW = outO + (size_t)NQ * DD;             // [65536][2048]
  u16* memb = (u16*)d_ws;                           // [2048][256] bf16
  u16* memTb = memb + (size_t)MM * DD;              // [256][2048] bf16

  mem_convert_kernel<<<dim3((MM * DD) / 256), dim3(256), 0, stream>>>(
      memory, memb, memTb);
  fused_kernel<<<dim3(NQ / 64), dim3(256), 0, stream>>>(x, memb, memTb, outO,
                                                        outW);
}

// Round 2
// 482.162 us; speedup vs baseline: 1.0985x; 1.0985x over previous
//
#include <hip/hip_runtime.h>
#include <hip/hip_bf16.h>
#include <stdint.h>

// x[65536][256] f32, memory[2048][256] f32
// out = [ memory_output[65536][256] | attention_weights[65536][2048] ] f32
#define NQ 65536
#define MM 2048
#define DD 256

typedef __bf16 bf16x8 __attribute__((ext_vector_type(8)));
typedef float f32x16 __attribute__((ext_vector_type(16)));
typedef unsigned short u16;
typedef unsigned int u32;

typedef __attribute__((address_space(3))) u32 lds_u32;
typedef __attribute__((address_space(1))) u32 glb_u32;

#define GLOAD16(gsrc, ldst)                                                    \
  __builtin_amdgcn_global_load_lds((glb_u32*)(uintptr_t)(gsrc),                \
                                   (lds_u32*)(u32)(uintptr_t)(ldst), 16, 0, 0)

__global__ __launch_bounds__(256) void mem_convert_kernel(
    const float* __restrict__ memory, u16* __restrict__ memb,
    u16* __restrict__ memTb) {
  int tid = blockIdx.x * 256 + threadIdx.x;  // 524288 total
  float v = memory[tid];
  u32 u = __builtin_bit_cast(u32, v);
  u += 0x7FFFu + ((u >> 16) & 1u);  // RTNE
  u16 b = (u16)(u >> 16);
  memb[tid] = b;
  int m = tid >> 8, d = tid & 255;
  memTb[d * MM + m] = b;
}

// 128 q-rows per block (4 waves x 32 rows), 32x32x16 MFMA.
// Phase 1: rowsums of exp(S) over MB=64 tiles. Phase 2: recompute S,
// write W, accumulate O, over MB=32 tiles. Double-buffered staging with
// prefetch-one-tile-ahead; one __syncthreads per tile.
__global__ __launch_bounds__(256, 2) void fused_kernel(
    const float* __restrict__ x, const u16* __restrict__ memb,
    const u16* __restrict__ memTb, float* __restrict__ outO,
    float* __restrict__ outW) {
  __shared__ __align__(16) char stage[2][32768];
  __shared__ __align__(16) u16 plds[4][32][40];  // per-wave P, 80B pitch

  const int tid = threadIdx.x;
  const int wv = tid >> 6;
  const int l = tid & 63;
  const int q5 = l & 31;  // lane row/col within 32
  const int h = l >> 5;   // K-half select
  const int qw = blockIdx.x * 128 + wv * 32;

  // ---- Q fragments: 32 rows x 256 dims per wave (A-frags for 32x32x16) ----
  bf16x8 aq[16];
  {
    const float* xrow = x + (size_t)(qw + q5) * DD;
#pragma unroll
    for (int ks = 0; ks < 16; ++ks) {
      const float4 f0 = *(const float4*)(xrow + ks * 16 + h * 8);
      const float4 f1 = *(const float4*)(xrow + ks * 16 + h * 8 + 4);
      bf16x8 a;
      a[0] = (__bf16)f0.x; a[1] = (__bf16)f0.y;
      a[2] = (__bf16)f0.z; a[3] = (__bf16)f0.w;
      a[4] = (__bf16)f1.x; a[5] = (__bf16)f1.y;
      a[6] = (__bf16)f1.z; a[7] = (__bf16)f1.w;
      aq[ks] = a;
    }
  }

  // ---- staging helpers (16B-chunk XOR swizzle on source + read) ----
  auto STAGE1 = [&](int mt, char* buf) {  // 64 mem rows -> 32KB
#pragma unroll
    for (int i = 0; i < 8; ++i) {
      const int wc = wv * 8 + i;   // 1KB chunk 0..31
      const int row = wc * 2 + h;  // 0..63
      const int csrc = q5 ^ (row & 7);
      GLOAD16(memb + (((size_t)(mt * 64 + row)) << 8) + csrc * 8,
              buf + (wc << 10));
    }
  };
  auto STAGE2 = [&](int t, char* buf) {  // 32 mem rows + 32 memT cols
#pragma unroll
    for (int i = 0; i < 4; ++i) {
      const int wc = wv * 4 + i;   // 0..15
      const int row = wc * 2 + h;  // 0..31
      const int csrc = q5 ^ (row & 7);
      GLOAD16(memb + (((size_t)(t * 32 + row)) << 8) + csrc * 8,
              buf + (wc << 10));
    }
#pragma unroll
    for (int i = 0; i < 4; ++i) {
      const int wc = wv * 4 + i;
      const int gci = (wc << 6) + l;  // 16B chunk 0..1023
      const int d = gci >> 2;
      const int ksrc = (gci & 3) ^ (d & 3);
      GLOAD16(memTb + (size_t)d * MM + t * 32 + ksrc * 8,
              buf + 16384 + (wc << 10));
    }
  };

  // ---- Phase 1: rowsums of exp(S) (|S| <= ~3, no max-sub needed) ----
  float part[16];
#pragma unroll
  for (int r = 0; r < 16; ++r) part[r] = 0.f;

  STAGE1(0, stage[0]);
  __syncthreads();
  for (int mt = 0; mt < 32; ++mt) {
    char* cur = stage[mt & 1];
    char* nxt = stage[(mt & 1) ^ 1];
    if (mt + 1 < 32) STAGE1(mt + 1, nxt);
    else STAGE2(0, nxt);  // prefetch phase-2 tile 0
#pragma unroll
    for (int msub = 0; msub < 2; ++msub) {
      const int mrow = msub * 32 + q5;
      const char* bbase = cur + mrow * 512;
      const int sw = mrow & 7;
      f32x16 acc = 0.f;
      __builtin_amdgcn_s_setprio(1);
#pragma unroll
      for (int ks = 0; ks < 16; ++ks) {
        bf16x8 b = *(const bf16x8*)(bbase + (((ks * 2 + h) ^ sw) << 4));
        acc = __builtin_amdgcn_mfma_f32_32x32x16_bf16(aq[ks], b, acc, 0, 0, 0);
      }
      __builtin_amdgcn_s_setprio(0);
#pragma unroll
      for (int r = 0; r < 16; ++r) part[r] += __expf(acc[r]);
    }
    __syncthreads();
  }

  // reduce rowsums across the 32 lanes sharing each q row
  float invs[16];
#pragma unroll
  for (int r = 0; r < 16; ++r) {
    float p = part[r];
    p += __shfl_xor(p, 1, 64);
    p += __shfl_xor(p, 2, 64);
    p += __shfl_xor(p, 4, 64);
    p += __shfl_xor(p, 8, 64);
    p += __shfl_xor(p, 16, 64);
    invs[r] = 1.0f / p;
  }

  // ---- Phase 2: recompute S, write W, accumulate O ----
  f32x16 oacc[8];
#pragma unroll
  for (int i = 0; i < 8; ++i) oacc[i] = 0.f;

  for (int t = 0; t < 64; ++t) {
    char* cur = stage[t & 1];
    char* nxt = stage[(t & 1) ^ 1];
    if (t + 1 < 64) STAGE2(t + 1, nxt);

    // QK: S tile 32q x 32m
    f32x16 acc = 0.f;
    {
      const char* bbase = cur + q5 * 512;
      const int sw = q5 & 7;
      __builtin_amdgcn_s_setprio(1);
#pragma unroll
      for (int ks = 0; ks < 16; ++ks) {
        bf16x8 b = *(const bf16x8*)(bbase + (((ks * 2 + h) ^ sw) << 4));
        acc = __builtin_amdgcn_mfma_f32_32x32x16_bf16(aq[ks], b, acc, 0, 0, 0);
      }
      __builtin_amdgcn_s_setprio(0);
    }

    // exp, W write, P (bf16, normalized) -> plds for lane transpose
#pragma unroll
    for (int r = 0; r < 16; ++r) {
      const int qrow = (r & 3) + 8 * (r >> 2) + 4 * h;
      const float w = __expf(acc[r]) * invs[r];
      outW[(size_t)(qw + qrow) * MM + t * 32 + q5] = w;
      plds[wv][qrow][q5] = __builtin_bit_cast(u16, (__bf16)w);
    }
    // wave-private roundtrip: drain writes before reads
    asm volatile("s_waitcnt lgkmcnt(0)" ::: "memory");

    // PV: O += P(32q x 32m) * M(32m x 256d)
    const char* tb = cur + 16384;
    __builtin_amdgcn_s_setprio(1);
#pragma unroll
    for (int ks2 = 0; ks2 < 2; ++ks2) {
      bf16x8 pa = *(const bf16x8*)&plds[wv][q5][ks2 * 16 + h * 8];
#pragma unroll
      for (int dsub = 0; dsub < 8; ++dsub) {
        const int d = dsub * 32 + q5;
        const int ch = (ks2 * 2 + h) ^ (d & 3);
        bf16x8 b = *(const bf16x8*)(tb + d * 64 + ch * 16);
        oacc[dsub] =
            __builtin_amdgcn_mfma_f32_32x32x16_bf16(pa, b, oacc[dsub], 0, 0, 0);
      }
    }
    __builtin_amdgcn_s_setprio(0);
    __syncthreads();
  }

#pragma unroll
  for (int dsub = 0; dsub < 8; ++dsub) {
#pragma unroll
    for (int r = 0; r < 16; ++r) {
      const int qrow = (r & 3) + 8 * (r >> 2) + 4 * h;
      outO[(size_t)(qw + qrow) * DD + dsub * 32 + q5] = oacc[dsub][r];
    }
  }
}

extern "C" void kernel_launch(void* const* d_in, const int* in_sizes, int n_in,
                              void* d_out, int out_size, void* d_ws,
                              size_t ws_size, hipStream_t stream) {
  const float* x = (const float*)d_in[0];
  const float* memory = (const float*)d_in[1];
  float* outO = (float*)d_out;           // [65536][256]
  float* outW = outO + (size_t)NQ * DD;  // [65536][2048]
  u16* memb = (u16*)d_ws;                // [2048][256] bf16
  u16* memTb = memb + (size_t)MM * DD;   // [256][2048] bf16

  mem_convert_kernel<<<dim3((MM * DD) / 256), dim3(256), 0, stream>>>(
      memory, memb, memTb);
  fused_kernel<<<dim3(NQ / 128), dim3(256), 0, stream>>>(x, memb, memTb, outO,
                                                         outW);
}

// Round 4
// 465.738 us; speedup vs baseline: 1.1372x; 1.0353x over previous
//
#include <hip/hip_runtime.h>
#include <hip/hip_bf16.h>
#include <stdint.h>

// x[65536][256] f32, memory[2048][256] f32
// out = [ memory_output[65536][256] | attention_weights[65536][2048] ] f32
#define NQ 65536
#define MM 2048
#define DD 256

typedef __bf16 bf16x8 __attribute__((ext_vector_type(8)));
typedef float f32x16 __attribute__((ext_vector_type(16)));
typedef unsigned short u16;
typedef unsigned int u32;

typedef __attribute__((address_space(3))) u32 lds_u32;
typedef __attribute__((address_space(1))) u32 glb_u32;

#define GLOAD16(gsrc, ldst)                                                    \
  __builtin_amdgcn_global_load_lds((glb_u32*)(uintptr_t)(gsrc),                \
                                   (lds_u32*)(u32)(uintptr_t)(ldst), 16, 0, 0)

// memb: row-major [2048][256] bf16.
// memTswz: per 32-m tile t (64 tiles, 16KB each):
//   u16 idx = t*8192 + (d*4 + slot)*8 + e, slot = c ^ ((d>>1)&3),
//   within-tile m = c*8 + e. Linear global_load_lds staging + swizzled PV
//   reads. This PV path was validated on HW in round 3 (output 0 passed).
__global__ __launch_bounds__(256) void mem_convert_kernel(
    const float* __restrict__ memory, u16* __restrict__ memb,
    u16* __restrict__ memTswz) {
  int tid = blockIdx.x * 256 + threadIdx.x;  // 524288 total
  float v = memory[tid];
  u32 u = __builtin_bit_cast(u32, v);
  u += 0x7FFFu + ((u >> 16) & 1u);  // RTNE
  u16 b = (u16)(u >> 16);
  memb[tid] = b;
  int m = tid >> 8, d = tid & 255;
  int t = m >> 5, mi = m & 31;
  int c = mi >> 3, e = mi & 7;
  int slot = c ^ ((d >> 1) & 3);
  memTswz[(size_t)t * 8192 + (size_t)(d * 4 + slot) * 8 + e] = b;
}

// ---- Pass 1: QK + exp -> outW holds UNNORMALIZED f32 e; sums per row ----
// 512 blocks x 4 waves x 32q. The e-store is R2's hardware-validated
// C/D-layout W store (minus the *inv factor).
__global__ __launch_bounds__(256, 2) void pass1_kernel(
    const float* __restrict__ x, const u16* __restrict__ memb,
    float* __restrict__ outW, float* __restrict__ sums) {
  __shared__ __align__(16) char stage[2][32768];

  const int tid = threadIdx.x;
  const int wv = tid >> 6;
  const int l = tid & 63;
  const int q5 = l & 31;
  const int h = l >> 5;
  const int qw = blockIdx.x * 128 + wv * 32;

  bf16x8 aq[16];
  {
    const float* xrow = x + (size_t)(qw + q5) * DD;
#pragma unroll
    for (int ks = 0; ks < 16; ++ks) {
      const float4 f0 = *(const float4*)(xrow + ks * 16 + h * 8);
      const float4 f1 = *(const float4*)(xrow + ks * 16 + h * 8 + 4);
      bf16x8 a;
      a[0] = (__bf16)f0.x; a[1] = (__bf16)f0.y;
      a[2] = (__bf16)f0.z; a[3] = (__bf16)f0.w;
      a[4] = (__bf16)f1.x; a[5] = (__bf16)f1.y;
      a[6] = (__bf16)f1.z; a[7] = (__bf16)f1.w;
      aq[ks] = a;
    }
  }

  auto STAGE1 = [&](int mt, char* buf) {  // 64 mem rows -> 32KB
#pragma unroll
    for (int i = 0; i < 8; ++i) {
      const int wc = wv * 8 + i;
      const int row = wc * 2 + h;
      const int csrc = q5 ^ (row & 7);
      GLOAD16(memb + (((size_t)(mt * 64 + row)) << 8) + csrc * 8,
              buf + (wc << 10));
    }
  };

  float part[16];
#pragma unroll
  for (int r = 0; r < 16; ++r) part[r] = 0.f;

  STAGE1(0, stage[0]);
  __syncthreads();
  for (int mt = 0; mt < 32; ++mt) {
    char* cur = stage[mt & 1];
    char* nxt = stage[(mt & 1) ^ 1];
    if (mt + 1 < 32) STAGE1(mt + 1, nxt);
#pragma unroll
    for (int msub = 0; msub < 2; ++msub) {
      const int mrow = msub * 32 + q5;
      const char* bbase = cur + mrow * 512;
      const int sw = mrow & 7;
      f32x16 acc = 0.f;
      __builtin_amdgcn_s_setprio(1);
#pragma unroll
      for (int ks = 0; ks < 16; ++ks) {
        bf16x8 b = *(const bf16x8*)(bbase + (((ks * 2 + h) ^ sw) << 4));
        acc = __builtin_amdgcn_mfma_f32_32x32x16_bf16(aq[ks], b, acc, 0, 0, 0);
      }
      __builtin_amdgcn_s_setprio(0);
      const int tm = mt * 2 + msub;
#pragma unroll
      for (int r = 0; r < 16; ++r) {
        const int qrow = (r & 3) + 8 * (r >> 2) + 4 * h;
        const float e = __expf(acc[r]);
        part[r] += e;
        outW[(size_t)(qw + qrow) * MM + tm * 32 + q5] = e;
      }
    }
    __syncthreads();
  }

#pragma unroll
  for (int r = 0; r < 16; ++r) {
    float p = part[r];
    p += __shfl_xor(p, 1, 64);
    p += __shfl_xor(p, 2, 64);
    p += __shfl_xor(p, 4, 64);
    p += __shfl_xor(p, 8, 64);
    p += __shfl_xor(p, 16, 64);
    if (q5 == 0) sums[qw + (r & 3) + 8 * (r >> 2) + 4 * h] = p;
  }
}

// ---- Pass 2: W *= 1/sum (in place, identity addressing) + O = W*M ----
// 512 blocks x 4 waves x 32q. PA-frags built from the very values being
// normalized; B from memTswz LDS staging (HW-validated in round 3).
__global__ __launch_bounds__(256, 2) void pass2_kernel(
    const u16* __restrict__ memTswz, const float* __restrict__ sums,
    float* __restrict__ outO, float* __restrict__ outW) {
  __shared__ __align__(16) char tstage[2][16384];

  const int tid = threadIdx.x;
  const int wv = tid >> 6;
  const int l = tid & 63;
  const int q5 = l & 31;
  const int h = l >> 5;
  const int qw = blockIdx.x * 128 + wv * 32;

  const float inv_lane = 1.0f / sums[qw + q5];

  auto STAGE = [&](int t, char* buf) {  // 16KB memT tile, linear
#pragma unroll
    for (int i = 0; i < 4; ++i) {
      const int ci = wv * 4 + i;
      GLOAD16(memTswz + ((size_t)t * 1024 + ci * 64 + l) * 8, buf + (ci << 10));
    }
  };

  f32x16 oacc[8];
#pragma unroll
  for (int i = 0; i < 8; ++i) oacc[i] = 0.f;

  STAGE(0, tstage[0]);
  __syncthreads();
  for (int tm = 0; tm < 64; ++tm) {
    char* cur = tstage[tm & 1];
    char* nxt = tstage[(tm & 1) ^ 1];
    if (tm + 1 < 64) STAGE(tm + 1, nxt);

    float* wrow = outW + (size_t)(qw + q5) * MM + tm * 32;
    bf16x8 pa[2];
#pragma unroll
    for (int ks2 = 0; ks2 < 2; ++ks2) {
      float4 f0 = *(const float4*)(wrow + ks2 * 16 + h * 8);
      float4 f1 = *(const float4*)(wrow + ks2 * 16 + h * 8 + 4);
      float w0 = f0.x * inv_lane, w1 = f0.y * inv_lane;
      float w2 = f0.z * inv_lane, w3 = f0.w * inv_lane;
      float w4 = f1.x * inv_lane, w5 = f1.y * inv_lane;
      float w6 = f1.z * inv_lane, w7 = f1.w * inv_lane;
      *(float4*)(wrow + ks2 * 16 + h * 8) = make_float4(w0, w1, w2, w3);
      *(float4*)(wrow + ks2 * 16 + h * 8 + 4) = make_float4(w4, w5, w6, w7);
      bf16x8 p;
      p[0] = (__bf16)w0; p[1] = (__bf16)w1; p[2] = (__bf16)w2;
      p[3] = (__bf16)w3; p[4] = (__bf16)w4; p[5] = (__bf16)w5;
      p[6] = (__bf16)w6; p[7] = (__bf16)w7;
      pa[ks2] = p;
    }

    __builtin_amdgcn_s_setprio(1);
#pragma unroll
    for (int ks2 = 0; ks2 < 2; ++ks2) {
#pragma unroll
      for (int dsub = 0; dsub < 8; ++dsub) {
        const int d = dsub * 32 + q5;
        const int slot = (2 * ks2 + h) ^ ((d >> 1) & 3);
        bf16x8 b = *(const bf16x8*)(cur + d * 64 + slot * 16);
        oacc[dsub] =
            __builtin_amdgcn_mfma_f32_32x32x16_bf16(pa[ks2], b, oacc[dsub], 0,
                                                    0, 0);
      }
    }
    __builtin_amdgcn_s_setprio(0);
    __syncthreads();
  }

#pragma unroll
  for (int dsub = 0; dsub < 8; ++dsub) {
#pragma unroll
    for (int r = 0; r < 16; ++r) {
      const int qrow = (r & 3) + 8 * (r >> 2) + 4 * h;
      outO[(size_t)(qw + qrow) * DD + dsub * 32 + q5] = oacc[dsub][r];
    }
  }
}

extern "C" void kernel_launch(void* const* d_in, const int* in_sizes, int n_in,
                              void* d_out, int out_size, void* d_ws,
                              size_t ws_size, hipStream_t stream) {
  const float* x = (const float*)d_in[0];
  const float* memory = (const float*)d_in[1];
  float* outO = (float*)d_out;           // [65536][256]
  float* outW = outO + (size_t)NQ * DD;  // [65536][2048]

  // ws layout: memb (1MB) | memTswz (1MB) | sums (256KB)
  u16* memb = (u16*)d_ws;
  u16* memTswz = memb + (size_t)MM * DD;
  float* sums = (float*)(memTswz + (size_t)MM * DD);

  mem_convert_kernel<<<dim3((MM * DD) / 256), dim3(256), 0, stream>>>(
      memory, memb, memTswz);
  pass1_kernel<<<dim3(NQ / 128), dim3(256), 0, stream>>>(x, memb, outW, sums);
  pass2_kernel<<<dim3(NQ / 128), dim3(256), 0, stream>>>(memTswz, sums, outO,
                                                         outW);
}

// Round 5
// 418.460 us; speedup vs baseline: 1.2657x; 1.1130x over previous
//
#include <hip/hip_runtime.h>
#include <hip/hip_bf16.h>
#include <stdint.h>

// x[65536][256] f32, memory[2048][256] f32
// out = [ memory_output[65536][256] | attention_weights[65536][2048] ] f32
#define NQ 65536
#define MM 2048
#define DD 256

typedef __bf16 bf16x8 __attribute__((ext_vector_type(8)));
typedef float f32x16 __attribute__((ext_vector_type(16)));
typedef unsigned short u16;
typedef unsigned int u32;
typedef u16 u16x8 __attribute__((ext_vector_type(8)));

typedef __attribute__((address_space(3))) u32 lds_u32;
typedef __attribute__((address_space(1))) u32 glb_u32;

#define GLOAD16(gsrc, ldst)                                                    \
  __builtin_amdgcn_global_load_lds((glb_u32*)(uintptr_t)(gsrc),                \
                                   (lds_u32*)(u32)(uintptr_t)(ldst), 16, 0, 0)

__device__ __forceinline__ u16 f32_to_bf16_rtne(float v) {
  u32 u = __builtin_bit_cast(u32, v);
  u += 0x7FFFu + ((u >> 16) & 1u);
  return (u16)(u >> 16);
}

// memb: row-major [2048][256] bf16.
// memTswz: per 32-m tile t (64 tiles, 16KB each):
//   u16 idx = t*8192 + (d*4 + slot)*8 + e, slot = c ^ ((d>>1)&3),
//   within-tile m = c*8 + e. Validated on HW (R3/R4 output 0).
__global__ __launch_bounds__(256) void mem_convert_kernel(
    const float* __restrict__ memory, u16* __restrict__ memb,
    u16* __restrict__ memTswz) {
  int tid = blockIdx.x * 256 + threadIdx.x;  // 524288 total
  u16 b = f32_to_bf16_rtne(memory[tid]);
  memb[tid] = b;
  int m = tid >> 8, d = tid & 255;
  int t = m >> 5, mi = m & 31;
  int c = mi >> 3, e = mi & 7;
  int slot = c ^ ((d >> 1) & 3);
  memTswz[(size_t)t * 8192 + (size_t)(d * 4 + slot) * 8 + e] = b;
}

// ---- Pass 1: QK + exp -> unnormalized e (bf16 p_ws or f32 outW) + sums ----
// 512 blocks x 4 waves x 32q. Identity [row][col] addressing for the e store
// (same C/D-layout scatter that passed in R2/R4).
template <bool STORE_BF16>
__global__ __launch_bounds__(256, 2) void pass1_kernel(
    const float* __restrict__ x, const u16* __restrict__ memb,
    u16* __restrict__ p_e, float* __restrict__ outWf,
    float* __restrict__ sums) {
  __shared__ __align__(16) char stage[2][32768];

  const int tid = threadIdx.x;
  const int wv = tid >> 6;
  const int l = tid & 63;
  const int q5 = l & 31;
  const int h = l >> 5;
  const int qw = blockIdx.x * 128 + wv * 32;

  bf16x8 aq[16];
  {
    const float* xrow = x + (size_t)(qw + q5) * DD;
#pragma unroll
    for (int ks = 0; ks < 16; ++ks) {
      const float4 f0 = *(const float4*)(xrow + ks * 16 + h * 8);
      const float4 f1 = *(const float4*)(xrow + ks * 16 + h * 8 + 4);
      bf16x8 a;
      a[0] = (__bf16)f0.x; a[1] = (__bf16)f0.y;
      a[2] = (__bf16)f0.z; a[3] = (__bf16)f0.w;
      a[4] = (__bf16)f1.x; a[5] = (__bf16)f1.y;
      a[6] = (__bf16)f1.z; a[7] = (__bf16)f1.w;
      aq[ks] = a;
    }
  }

  auto STAGE1 = [&](int mt, char* buf) {  // 64 mem rows -> 32KB
#pragma unroll
    for (int i = 0; i < 8; ++i) {
      const int wc = wv * 8 + i;
      const int row = wc * 2 + h;
      const int csrc = q5 ^ (row & 7);
      GLOAD16(memb + (((size_t)(mt * 64 + row)) << 8) + csrc * 8,
              buf + (wc << 10));
    }
  };

  float part[16];
#pragma unroll
  for (int r = 0; r < 16; ++r) part[r] = 0.f;

  STAGE1(0, stage[0]);
  __syncthreads();
  for (int mt = 0; mt < 32; ++mt) {
    char* cur = stage[mt & 1];
    char* nxt = stage[(mt & 1) ^ 1];
    if (mt + 1 < 32) STAGE1(mt + 1, nxt);
#pragma unroll
    for (int msub = 0; msub < 2; ++msub) {
      const int mrow = msub * 32 + q5;
      const char* bbase = cur + mrow * 512;
      const int sw = mrow & 7;
      f32x16 acc = 0.f;
      __builtin_amdgcn_s_setprio(1);
#pragma unroll
      for (int ks = 0; ks < 16; ++ks) {
        bf16x8 b = *(const bf16x8*)(bbase + (((ks * 2 + h) ^ sw) << 4));
        acc = __builtin_amdgcn_mfma_f32_32x32x16_bf16(aq[ks], b, acc, 0, 0, 0);
      }
      __builtin_amdgcn_s_setprio(0);
      const int tm = mt * 2 + msub;
#pragma unroll
      for (int r = 0; r < 16; ++r) {
        const int qrow = (r & 3) + 8 * (r >> 2) + 4 * h;
        const float e = __expf(acc[r]);
        part[r] += e;
        if (STORE_BF16) {
          p_e[(size_t)(qw + qrow) * MM + tm * 32 + q5] = f32_to_bf16_rtne(e);
        } else {
          outWf[(size_t)(qw + qrow) * MM + tm * 32 + q5] = e;
        }
      }
    }
    __syncthreads();
  }

#pragma unroll
  for (int r = 0; r < 16; ++r) {
    float p = part[r];
    p += __shfl_xor(p, 1, 64);
    p += __shfl_xor(p, 2, 64);
    p += __shfl_xor(p, 4, 64);
    p += __shfl_xor(p, 8, 64);
    p += __shfl_xor(p, 16, 64);
    if (q5 == 0) sums[qw + (r & 3) + 8 * (r >> 2) + 4 * h] = p;
  }
}

// ---- Pass 2: W = e*inv (identity addressing) + O = (e*M)*inv ----
// 512 blocks x 4 waves x 32q. PA frags are the raw stored bf16 bits
// (unnormalized); O scaled at the end by invr (shfl path validated in R3).
template <bool LOAD_BF16>
__global__ __launch_bounds__(256, 2) void pass2_kernel(
    const u16* __restrict__ p_e, const u16* __restrict__ memTswz,
    const float* __restrict__ sums, float* __restrict__ outO,
    float* __restrict__ outW) {
  __shared__ __align__(16) char tstage[2][16384];

  const int tid = threadIdx.x;
  const int wv = tid >> 6;
  const int l = tid & 63;
  const int q5 = l & 31;
  const int h = l >> 5;
  const int qw = blockIdx.x * 128 + wv * 32;

  const float inv_lane = 1.0f / sums[qw + q5];
  float invr[16];
#pragma unroll
  for (int r = 0; r < 16; ++r) {
    invr[r] = __shfl(inv_lane, (r & 3) + 8 * (r >> 2) + 4 * h, 64);
  }

  auto STAGE = [&](int t, char* buf) {  // 16KB memT tile, linear
#pragma unroll
    for (int i = 0; i < 4; ++i) {
      const int ci = wv * 4 + i;
      GLOAD16(memTswz + ((size_t)t * 1024 + ci * 64 + l) * 8, buf + (ci << 10));
    }
  };

  f32x16 oacc[8];
#pragma unroll
  for (int i = 0; i < 8; ++i) oacc[i] = 0.f;

  STAGE(0, tstage[0]);
  __syncthreads();
  for (int tm = 0; tm < 64; ++tm) {
    char* cur = tstage[tm & 1];
    char* nxt = tstage[(tm & 1) ^ 1];
    if (tm + 1 < 64) STAGE(tm + 1, nxt);

    bf16x8 pa[2];
    if (LOAD_BF16) {
      const u16* prow = p_e + (size_t)(qw + q5) * MM + tm * 32;
#pragma unroll
      for (int ks2 = 0; ks2 < 2; ++ks2) {
        u16x8 pe = *(const u16x8*)(prow + ks2 * 16 + h * 8);
        pa[ks2] = __builtin_bit_cast(bf16x8, pe);  // unnormalized e
        float w[8];
#pragma unroll
        for (int j = 0; j < 8; ++j) {
          w[j] = __builtin_bit_cast(float, (u32)pe[j] << 16) * inv_lane;
        }
        float* base =
            outW + (size_t)(qw + q5) * MM + tm * 32 + ks2 * 16 + h * 8;
        *(float4*)base = make_float4(w[0], w[1], w[2], w[3]);
        *(float4*)(base + 4) = make_float4(w[4], w[5], w[6], w[7]);
      }
    } else {
      float* wrow = outW + (size_t)(qw + q5) * MM + tm * 32;
#pragma unroll
      for (int ks2 = 0; ks2 < 2; ++ks2) {
        float4 f0 = *(const float4*)(wrow + ks2 * 16 + h * 8);
        float4 f1 = *(const float4*)(wrow + ks2 * 16 + h * 8 + 4);
        float w0 = f0.x * inv_lane, w1 = f0.y * inv_lane;
        float w2 = f0.z * inv_lane, w3 = f0.w * inv_lane;
        float w4 = f1.x * inv_lane, w5 = f1.y * inv_lane;
        float w6 = f1.z * inv_lane, w7 = f1.w * inv_lane;
        *(float4*)(wrow + ks2 * 16 + h * 8) = make_float4(w0, w1, w2, w3);
        *(float4*)(wrow + ks2 * 16 + h * 8 + 4) = make_float4(w4, w5, w6, w7);
        bf16x8 p;
        p[0] = (__bf16)(w0 * 1.0f); p[1] = (__bf16)w1; p[2] = (__bf16)w2;
        p[3] = (__bf16)w3; p[4] = (__bf16)w4; p[5] = (__bf16)w5;
        p[6] = (__bf16)w6; p[7] = (__bf16)w7;
        pa[ks2] = p;
      }
    }

    __builtin_amdgcn_s_setprio(1);
#pragma unroll
    for (int ks2 = 0; ks2 < 2; ++ks2) {
#pragma unroll
      for (int dsub = 0; dsub < 8; ++dsub) {
        const int d = dsub * 32 + q5;
        const int slot = (2 * ks2 + h) ^ ((d >> 1) & 3);
        bf16x8 b = *(const bf16x8*)(cur + d * 64 + slot * 16);
        oacc[dsub] =
            __builtin_amdgcn_mfma_f32_32x32x16_bf16(pa[ks2], b, oacc[dsub], 0,
                                                    0, 0);
      }
    }
    __builtin_amdgcn_s_setprio(0);
    __syncthreads();
  }

#pragma unroll
  for (int dsub = 0; dsub < 8; ++dsub) {
#pragma unroll
    for (int r = 0; r < 16; ++r) {
      const int qrow = (r & 3) + 8 * (r >> 2) + 4 * h;
      const float scale = LOAD_BF16 ? invr[r] : 1.0f;
      outO[(size_t)(qw + qrow) * DD + dsub * 32 + q5] = oacc[dsub][r] * scale;
    }
  }
}

extern "C" void kernel_launch(void* const* d_in, const int* in_sizes, int n_in,
                              void* d_out, int out_size, void* d_ws,
                              size_t ws_size, hipStream_t stream) {
  const float* x = (const float*)d_in[0];
  const float* memory = (const float*)d_in[1];
  float* outO = (float*)d_out;           // [65536][256]
  float* outW = outO + (size_t)NQ * DD;  // [65536][2048]

  // ws layout: memb (1MB) | memTswz (1MB) | sums (256KB) | p_e (256MB bf16)
  u16* memb = (u16*)d_ws;
  u16* memTswz = memb + (size_t)MM * DD;
  float* sums = (float*)(memTswz + (size_t)MM * DD);
  u16* p_e = (u16*)(sums + NQ);
  const size_t need = (size_t)MM * DD * 2 * 2 + (size_t)NQ * 4 +
                      (size_t)NQ * MM * 2;  // ~258.25 MB (R3 proved ws fits)

  mem_convert_kernel<<<dim3((MM * DD) / 256), dim3(256), 0, stream>>>(
      memory, memb, memTswz);
  if (ws_size >= need) {
    pass1_kernel<true><<<dim3(NQ / 128), dim3(256), 0, stream>>>(
        x, memb, p_e, outW, sums);
    pass2_kernel<true><<<dim3(NQ / 128), dim3(256), 0, stream>>>(
        p_e, memTswz, sums, outO, outW);
  } else {
    pass1_kernel<false><<<dim3(NQ / 128), dim3(256), 0, stream>>>(
        x, memb, p_e, outW, sums);
    pass2_kernel<false><<<dim3(NQ / 128), dim3(256), 0, stream>>>(
        p_e, memTswz, sums, outO, outW);
  }
}